// Round 5
// baseline (96.922 us; speedup 1.0000x reference)
//
#include <hip/hip_runtime.h>
#include <cmath>

constexpr int B_ = 16, N_ = 10, H_ = 400, W_ = 400;
constexpr int HW = H_ * W_;              // 160000
constexpr int BN = B_ * N_;              // 160
constexpr int SPLITS = 16;               // stripes per image
constexpr int CHUNK4 = HW / 4 / SPLITS;  // 2500 float4s per stripe
constexpr int NBLK = BN * SPLITS;        // 2560 blocks

// ws layout (floats; every partial slot written every call -> no zeroing):
//   [0, NBLK)            overlap partials, slot = blockIdx
//   [OFF_I, OFF_I+NBLK)  inter partials
//   [OFF_T, OFF_T+B_*SPLITS) tgt_area partials (n==0 blocks)
//   [OFF_C]              ticket counter (as unsigned; memset to 0 each call)
constexpr int OFF_I = NBLK;
constexpr int OFF_T = 2 * NBLK;
constexpr int OFF_C = OFF_T + B_ * SPLITS;

__global__ void __launch_bounds__(256)
fused_k(const float4* __restrict__ om, const float4* __restrict__ tm,
        const float* __restrict__ bboxes, float* __restrict__ ws,
        float* __restrict__ out) {
    __shared__ float smO[4], smI[4], smT[4];
    __shared__ int amLast;
    int bn = blockIdx.x / SPLITS;
    int s  = blockIdx.x % SPLITS;
    int b  = bn / N_;
    int n  = bn % N_;

    float4 bb = reinterpret_cast<const float4*>(bboxes)[bn];
    int x1 = (int)floorf(bb.x), y1 = (int)floorf(bb.y);
    int x2 = (int)floorf(bb.z), y2 = (int)floorf(bb.w);

    const float4* omp = om + (size_t)bn * (HW / 4) + (size_t)s * CHUNK4;
    const float4* tmp = tm + (size_t)b  * (HW / 4) + (size_t)s * CHUNK4;
    int fbase = s * CHUNK4 * 4;

    float accO = 0.0f, accI = 0.0f, accT = 0.0f;
    for (int i = threadIdx.x; i < CHUNK4; i += 256) {
        float4 o = omp[i];
        float4 t = tmp[i];
        accO += o.x * t.x + o.y * t.y + o.z * t.z + o.w * t.w;
        accT += t.x + t.y + t.z + t.w;
        int fi = fbase + i * 4;
        int r  = fi / W_;          // W_=400: float4 spans 4 cols of one row
        int c  = fi - r * W_;
        if (r >= y1 && r < y2) {
            float ix = (c     >= x1 && c     < x2) ? t.x : 0.0f;
            float iy = (c + 1 >= x1 && c + 1 < x2) ? t.y : 0.0f;
            float iz = (c + 2 >= x1 && c + 2 < x2) ? t.z : 0.0f;
            float iw = (c + 3 >= x1 && c + 3 < x2) ? t.w : 0.0f;
            accI += ix + iy + iz + iw;
        }
    }
#pragma unroll
    for (int off = 32; off > 0; off >>= 1) {
        accO += __shfl_down(accO, off, 64);
        accI += __shfl_down(accI, off, 64);
        accT += __shfl_down(accT, off, 64);
    }
    int lane = threadIdx.x & 63, wid = threadIdx.x >> 6;
    if (lane == 0) { smO[wid] = accO; smI[wid] = accI; smT[wid] = accT; }
    __syncthreads();
    if (threadIdx.x == 0) {
        int slot = blockIdx.x;
        ws[slot]         = smO[0] + smO[1] + smO[2] + smO[3];
        ws[OFF_I + slot] = smI[0] + smI[1] + smI[2] + smI[3];
        if (n == 0)
            ws[OFF_T + b * SPLITS + s] = smT[0] + smT[1] + smT[2] + smT[3];
        __threadfence();  // release: flush partials past XCD L2
        unsigned old = atomicAdd(reinterpret_cast<unsigned*>(ws + OFF_C), 1u);
        amLast = (old == (unsigned)(NBLK - 1));
    }
    __syncthreads();
    if (amLast) {
        __threadfence();  // acquire: invalidate stale L2 lines
        int obn = threadIdx.x;
        if (obn < BN) {
            int ob = obn / N_;
            float ov = 0.0f, inter = 0.0f, tgt = 0.0f;
#pragma unroll
            for (int t = 0; t < SPLITS; ++t) {
                ov    += ws[obn * SPLITS + t];
                inter += ws[OFF_I + obn * SPLITS + t];
                tgt   += ws[OFF_T + ob * SPLITS + t];
            }
            float4 obb = reinterpret_cast<const float4*>(bboxes)[obn];
            int ox1 = (int)floorf(obb.x), oy1 = (int)floorf(obb.y);
            int ox2 = (int)floorf(obb.z), oy2 = (int)floorf(obb.w);
            float cr = (float)max(0, min(oy2, H_) - max(oy1, 0));
            float cc = (float)max(0, min(ox2, W_) - max(ox1, 0));
            float box_area = cr * cc;
            float iou = inter / (box_area + tgt - inter + 1e-8f);
            out[obn * 2 + 0] = ov;
            out[obn * 2 + 1] = iou;
        }
    }
}

extern "C" void kernel_launch(void* const* d_in, const int* in_sizes, int n_in,
                              void* d_out, int out_size, void* d_ws, size_t ws_size,
                              hipStream_t stream) {
    const float*  bboxes = (const float*)d_in[0];
    const float4* om     = (const float4*)d_in[1];
    const float4* tm     = (const float4*)d_in[2];
    float* out = (float*)d_out;
    float* ws  = (float*)d_ws;

    // zero the ticket counter (4 bytes) — required after harness 0xAA poison
    hipMemsetAsync((char*)d_ws + OFF_C * sizeof(float), 0, 4, stream);
    fused_k<<<NBLK, 256, 0, stream>>>(om, tm, bboxes, ws, out);
}

// Round 6
// 55.517 us; speedup vs baseline: 1.7458x; 1.7458x over previous
//
#include <hip/hip_runtime.h>
#include <cmath>

constexpr int B_ = 16, N_ = 10, H_ = 400, W_ = 400;
constexpr int HW = H_ * W_;              // 160000
constexpr int BN = B_ * N_;              // 160
constexpr int SPLITS = 16;               // stripes per image
constexpr int CHUNK4 = HW / 4 / SPLITS;  // 2500 float4s per stripe
constexpr int NBLK = BN * SPLITS;        // 2560 blocks

// ws layout (all zeroed by a 1.4KB memset each call):
//   [0, BN)        overlap accumulators (atomicAdd)
//   [BN, 2*BN)     inter accumulators
//   [2*BN, 2*BN+B_) tgt_area accumulators
//   [2*BN+B_]      ticket counter (unsigned)
constexpr int OFF_I = BN;
constexpr int OFF_T = 2 * BN;
constexpr int OFF_C = 2 * BN + B_;
constexpr int WS_N  = OFF_C + 1;

__global__ void __launch_bounds__(256)
fused_k(const float4* __restrict__ om, const float4* __restrict__ tm,
        const float* __restrict__ bboxes, float* __restrict__ ws,
        float* __restrict__ out) {
    __shared__ float smO[4], smI[4], smT[4];
    __shared__ int amLast;
    int bn = blockIdx.x / SPLITS;
    int s  = blockIdx.x % SPLITS;
    int b  = bn / N_;
    int n  = bn % N_;

    float4 bb = reinterpret_cast<const float4*>(bboxes)[bn];
    int x1 = (int)floorf(bb.x), y1 = (int)floorf(bb.y);
    int x2 = (int)floorf(bb.z), y2 = (int)floorf(bb.w);

    const float4* omp = om + (size_t)bn * (HW / 4) + (size_t)s * CHUNK4;
    const float4* tmp = tm + (size_t)b  * (HW / 4) + (size_t)s * CHUNK4;
    int fbase = s * CHUNK4 * 4;

    float accO = 0.0f, accI = 0.0f, accT = 0.0f;
    for (int i = threadIdx.x; i < CHUNK4; i += 256) {
        float4 o = omp[i];
        float4 t = tmp[i];
        accO += o.x * t.x + o.y * t.y + o.z * t.z + o.w * t.w;
        accT += t.x + t.y + t.z + t.w;
        int fi = fbase + i * 4;
        int r  = fi / W_;          // W_=400: float4 spans 4 cols of one row
        int c  = fi - r * W_;
        if (r >= y1 && r < y2) {
            float ix = (c     >= x1 && c     < x2) ? t.x : 0.0f;
            float iy = (c + 1 >= x1 && c + 1 < x2) ? t.y : 0.0f;
            float iz = (c + 2 >= x1 && c + 2 < x2) ? t.z : 0.0f;
            float iw = (c + 3 >= x1 && c + 3 < x2) ? t.w : 0.0f;
            accI += ix + iy + iz + iw;
        }
    }
#pragma unroll
    for (int off = 32; off > 0; off >>= 1) {
        accO += __shfl_down(accO, off, 64);
        accI += __shfl_down(accI, off, 64);
        accT += __shfl_down(accT, off, 64);
    }
    int lane = threadIdx.x & 63, wid = threadIdx.x >> 6;
    if (lane == 0) { smO[wid] = accO; smI[wid] = accI; smT[wid] = accT; }
    __syncthreads();
    if (threadIdx.x == 0) {
        // device-scope RMWs at the coherent point — no cache fences needed
        atomicAdd(&ws[bn],         smO[0] + smO[1] + smO[2] + smO[3]);
        atomicAdd(&ws[OFF_I + bn], smI[0] + smI[1] + smI[2] + smI[3]);
        if (n == 0)
            atomicAdd(&ws[OFF_T + b], smT[0] + smT[1] + smT[2] + smT[3]);
        // order: my adds complete before my ticket (per-wave wait, cheap)
        asm volatile("s_waitcnt vmcnt(0)" ::: "memory");
        unsigned old = __hip_atomic_fetch_add(
            reinterpret_cast<unsigned*>(ws + OFF_C), 1u,
            __ATOMIC_RELAXED, __HIP_MEMORY_SCOPE_AGENT);
        amLast = (old == (unsigned)(NBLK - 1));
    }
    __syncthreads();
    if (amLast) {
        int obn = threadIdx.x;
        if (obn < BN) {
            // agent-scope loads read the coherent point (bypass stale L2)
            float ov    = __hip_atomic_load(&ws[obn],
                              __ATOMIC_RELAXED, __HIP_MEMORY_SCOPE_AGENT);
            float inter = __hip_atomic_load(&ws[OFF_I + obn],
                              __ATOMIC_RELAXED, __HIP_MEMORY_SCOPE_AGENT);
            float tgt   = __hip_atomic_load(&ws[OFF_T + obn / N_],
                              __ATOMIC_RELAXED, __HIP_MEMORY_SCOPE_AGENT);
            float4 obb = reinterpret_cast<const float4*>(bboxes)[obn];
            int ox1 = (int)floorf(obb.x), oy1 = (int)floorf(obb.y);
            int ox2 = (int)floorf(obb.z), oy2 = (int)floorf(obb.w);
            float cr = (float)max(0, min(oy2, H_) - max(oy1, 0));
            float cc = (float)max(0, min(ox2, W_) - max(ox1, 0));
            float box_area = cr * cc;
            float iou = inter / (box_area + tgt - inter + 1e-8f);
            out[obn * 2 + 0] = ov;
            out[obn * 2 + 1] = iou;
        }
    }
}

extern "C" void kernel_launch(void* const* d_in, const int* in_sizes, int n_in,
                              void* d_out, int out_size, void* d_ws, size_t ws_size,
                              hipStream_t stream) {
    const float*  bboxes = (const float*)d_in[0];
    const float4* om     = (const float4*)d_in[1];
    const float4* tm     = (const float4*)d_in[2];
    float* out = (float*)d_out;
    float* ws  = (float*)d_ws;

    // zero accumulators + ticket counter (1.4 KB) each call
    hipMemsetAsync(d_ws, 0, WS_N * sizeof(float), stream);
    fused_k<<<NBLK, 256, 0, stream>>>(om, tm, bboxes, ws, out);
}

// Round 7
// 24.955 us; speedup vs baseline: 3.8839x; 2.2247x over previous
//
#include <hip/hip_runtime.h>
#include <cmath>

constexpr int B_ = 16, N_ = 10, H_ = 400, W_ = 400;
constexpr int HW = H_ * W_;              // 160000
constexpr int BN = B_ * N_;              // 160
constexpr int SPLITS = 8;                // stripes per image; 1280 blocks co-resident
constexpr int CHUNK4 = HW / 4 / SPLITS;  // 5000 float4s per stripe
constexpr int NBLK = BN * SPLITS;        // 1280

// ws layout (distinct slot per block, every slot written every call -> no
// zeroing, no atomics):
//   [0, NBLK)               overlap partials, slot = blockIdx
//   [OFF_I, OFF_I+NBLK)     inter partials
//   [OFF_T, OFF_T+B_*SPLITS) tgt_area partials (n==0 blocks)
constexpr int OFF_I = NBLK;
constexpr int OFF_T = 2 * NBLK;

__device__ __forceinline__ void body(const float4& o, const float4& t,
                                     int fi, int x1, int y1, int x2, int y2,
                                     float& accO, float& accT, float& accI) {
    accO += o.x * t.x + o.y * t.y + o.z * t.z + o.w * t.w;
    accT += t.x + t.y + t.z + t.w;
    int r = fi / W_;           // W_=400: a float4 never crosses a row
    int c = fi - r * W_;
    if (r >= y1 && r < y2) {
        float ix = (c     >= x1 && c     < x2) ? t.x : 0.0f;
        float iy = (c + 1 >= x1 && c + 1 < x2) ? t.y : 0.0f;
        float iz = (c + 2 >= x1 && c + 2 < x2) ? t.z : 0.0f;
        float iw = (c + 3 >= x1 && c + 3 < x2) ? t.w : 0.0f;
        accI += ix + iy + iz + iw;
    }
}

__global__ void __launch_bounds__(256)
fused_k(const float4* __restrict__ om, const float4* __restrict__ tm,
        const float* __restrict__ bboxes, float* __restrict__ ws) {
    __shared__ float smO[4], smI[4], smT[4];
    int bn = blockIdx.x / SPLITS;
    int s  = blockIdx.x % SPLITS;
    int b  = bn / N_;
    int n  = bn % N_;

    float4 bb = reinterpret_cast<const float4*>(bboxes)[bn];
    int x1 = (int)floorf(bb.x), y1 = (int)floorf(bb.y);
    int x2 = (int)floorf(bb.z), y2 = (int)floorf(bb.w);

    const float4* omp = om + (size_t)bn * (HW / 4) + (size_t)s * CHUNK4;
    const float4* tmp = tm + (size_t)b  * (HW / 4) + (size_t)s * CHUNK4;
    int fbase = s * CHUNK4 * 4;

    // two independent accumulator sets + 2-deep unroll: >=2 float4 pairs in
    // flight regardless of register allocation (guards vs the R6 collapse)
    float accO0 = 0.f, accT0 = 0.f, accI0 = 0.f;
    float accO1 = 0.f, accT1 = 0.f, accI1 = 0.f;
    for (int i = threadIdx.x; i < CHUNK4; i += 512) {
        float4 o0 = omp[i];
        float4 t0 = tmp[i];
        int j = i + 256;
        if (j < CHUNK4) {
            float4 o1 = omp[j];
            float4 t1 = tmp[j];
            body(o1, t1, fbase + j * 4, x1, y1, x2, y2, accO1, accT1, accI1);
        }
        body(o0, t0, fbase + i * 4, x1, y1, x2, y2, accO0, accT0, accI0);
    }
    float accO = accO0 + accO1, accT = accT0 + accT1, accI = accI0 + accI1;

#pragma unroll
    for (int off = 32; off > 0; off >>= 1) {
        accO += __shfl_down(accO, off, 64);
        accI += __shfl_down(accI, off, 64);
        accT += __shfl_down(accT, off, 64);
    }
    int lane = threadIdx.x & 63, wid = threadIdx.x >> 6;
    if (lane == 0) { smO[wid] = accO; smI[wid] = accI; smT[wid] = accT; }
    __syncthreads();
    if (threadIdx.x == 0) {
        ws[blockIdx.x]         = smO[0] + smO[1] + smO[2] + smO[3];
        ws[OFF_I + blockIdx.x] = smI[0] + smI[1] + smI[2] + smI[3];
        if (n == 0)
            ws[OFF_T + b * SPLITS + s] = smT[0] + smT[1] + smT[2] + smT[3];
    }
}

__global__ void __launch_bounds__(256)
finalize_k(const float* __restrict__ bboxes, const float* __restrict__ ws,
           float* __restrict__ out) {
    int bn = threadIdx.x;
    if (bn >= BN) return;
    int b = bn / N_;
    float ov = 0.0f, inter = 0.0f, tgt = 0.0f;
#pragma unroll
    for (int s = 0; s < SPLITS; ++s) {
        ov    += ws[bn * SPLITS + s];
        inter += ws[OFF_I + bn * SPLITS + s];
        tgt   += ws[OFF_T + b * SPLITS + s];
    }
    float4 bb = reinterpret_cast<const float4*>(bboxes)[bn];
    int x1 = (int)floorf(bb.x), y1 = (int)floorf(bb.y);
    int x2 = (int)floorf(bb.z), y2 = (int)floorf(bb.w);
    float cr = (float)max(0, min(y2, H_) - max(y1, 0));
    float cc = (float)max(0, min(x2, W_) - max(x1, 0));
    float box_area = cr * cc;
    float iou = inter / (box_area + tgt - inter + 1e-8f);
    out[bn * 2 + 0] = ov;
    out[bn * 2 + 1] = iou;
}

extern "C" void kernel_launch(void* const* d_in, const int* in_sizes, int n_in,
                              void* d_out, int out_size, void* d_ws, size_t ws_size,
                              hipStream_t stream) {
    const float*  bboxes = (const float*)d_in[0];
    const float4* om     = (const float4*)d_in[1];
    const float4* tm     = (const float4*)d_in[2];
    float* out = (float*)d_out;
    float* ws  = (float*)d_ws;

    fused_k<<<NBLK, 256, 0, stream>>>(om, tm, bboxes, ws);
    finalize_k<<<1, 256, 0, stream>>>(bboxes, ws, out);
}